// Round 1
// baseline (799.400 us; speedup 1.0000x reference)
//
#include <hip/hip_runtime.h>

#define LEAKY_SLOPE 0.01f

__device__ __forceinline__ float leaky_f(float x) { return x > 0.f ? x : LEAKY_SLOPE * x; }

// ---------------------------------------------------------------------------
// Combine THETAS (compile-time, D=2) with W3 (192x64):
//   M[k*64 + r][c] = sum_t theta[t][k] * W3[t*64 + r][c],  k = 0..2
// so branch_out = h@M0 + f1@M1 + f2@M2 + b3.
// ---------------------------------------------------------------------------
__global__ void compute_M(const float* __restrict__ W3, float* __restrict__ M) {
    int idx = blockIdx.x * blockDim.x + threadIdx.x;
    if (idx >= 192 * 64) return;
    int c = idx & 63;
    int r = (idx >> 6) & 63;
    int k = idx >> 12;  // 0..2
    const float TH[3][3] = {{3.f, -3.f, 0.75f},
                            {0.f,  3.f, -1.5f},
                            {0.f,  0.f, 0.75f}};
    float v = 0.f;
    #pragma unroll
    for (int t = 0; t < 3; t++) v += TH[t][k] * W3[(t * 64 + r) * 64 + c];
    M[idx] = v;
}

// ---------------------------------------------------------------------------
// Graph build: degree count (int atomics), hierarchical exclusive scan,
// counting-sort scatter into CSR (esrc grouped by dst).
// ---------------------------------------------------------------------------
__global__ void deg_kernel(const int* __restrict__ dst, int* __restrict__ deg, int E) {
    int e = blockIdx.x * blockDim.x + threadIdx.x;
    if (e < E) atomicAdd(&deg[dst[e]], 1);
}

__global__ void scan1(const int* __restrict__ deg, int* __restrict__ incl,
                      int* __restrict__ bsum, int n) {
    __shared__ int sm[1024];
    int i = blockIdx.x * 1024 + threadIdx.x;
    int v = (i < n) ? deg[i] : 0;
    sm[threadIdx.x] = v;
    __syncthreads();
    for (int off = 1; off < 1024; off <<= 1) {
        int a = (threadIdx.x >= (unsigned)off) ? sm[threadIdx.x - off] : 0;
        __syncthreads();
        sm[threadIdx.x] += a;
        __syncthreads();
    }
    if (i < n) incl[i] = sm[threadIdx.x];
    if (threadIdx.x == 1023) bsum[blockIdx.x] = sm[1023];
}

__global__ void scan2(int* __restrict__ bsum, int nb) {
    if (blockIdx.x == 0 && threadIdx.x == 0) {
        int run = 0;
        for (int b = 0; b < nb; b++) { int t = bsum[b]; bsum[b] = run; run += t; }
    }
}

__global__ void scan3(const int* __restrict__ incl, const int* __restrict__ bsum,
                      const int* __restrict__ deg, int* __restrict__ rowptr,
                      int* __restrict__ cursor, float* __restrict__ dinv, int n) {
    int i = blockIdx.x * blockDim.x + threadIdx.x;
    if (i >= n) return;
    int inc = incl[i] + bsum[i >> 10];
    int d = deg[i];
    rowptr[i + 1] = inc;
    cursor[i] = inc - d;  // exclusive scan = scatter base
    if (i == 0) rowptr[0] = 0;
    float df = (float)(d < 1 ? 1 : d);
    dinv[i] = 1.0f / sqrtf(df);
}

__global__ void scatter_kernel(const int* __restrict__ src, const int* __restrict__ dst,
                               int* __restrict__ cursor, int* __restrict__ esrc, int E) {
    int e = blockIdx.x * blockDim.x + threadIdx.x;
    if (e >= E) return;
    int pos = atomicAdd(&cursor[dst[e]], 1);
    esrc[pos] = src[e];
}

// ---------------------------------------------------------------------------
// SpMM: one wave per dst node, lane = feature (64 = H exactly).
//   F[v, out_off+j] = F[v, in_off+j] - dinv[v] * sum_{e: dst=v} F[src_e, in_off+j]*dinv[src_e]
// Feature buffer F is N x 192 (cols 0:64 = h, 64:128 = f1, 128:192 = f2) so
// the final GEMM reads contiguous 192-float rows.
// ---------------------------------------------------------------------------
__global__ void spmm_kernel(float* __restrict__ F, int in_off, int out_off,
                            const int* __restrict__ rowptr, const int* __restrict__ esrc,
                            const float* __restrict__ dinv, int n) {
    int w = (blockIdx.x * blockDim.x + threadIdx.x) >> 6;
    int j = threadIdx.x & 63;
    if (w >= n) return;
    int beg = rowptr[w];
    int end = rowptr[w + 1];
    float acc = 0.f;
    for (int e = beg; e < end; e++) {
        int s = esrc[e];
        acc += F[(size_t)s * 192 + in_off + j] * dinv[s];
    }
    float self = F[(size_t)w * 192 + in_off + j];
    F[(size_t)w * 192 + out_off + j] = self - acc * dinv[w];
}

// ---------------------------------------------------------------------------
// Row-parallel dense GEMM: out_row = [leaky](A_row @ W + bias) [+= existing]
// One thread per row, 64 accumulators, W loads are wave-uniform -> s_load.
// ---------------------------------------------------------------------------
template <int K, bool LEAKY, bool ACCUM>
__global__ void gemm64(const float* __restrict__ A, int lda,
                       const float* __restrict__ W, const float* __restrict__ bias,
                       float* __restrict__ out, int ldo, int n) {
    int row = blockIdx.x * blockDim.x + threadIdx.x;
    if (row >= n) return;
    float acc[64];
    #pragma unroll
    for (int j = 0; j < 64; j++) acc[j] = bias[j];
    const float4* arow = reinterpret_cast<const float4*>(A + (size_t)row * lda);
    #pragma unroll 1
    for (int k4 = 0; k4 < K / 4; k4++) {
        float4 a = arow[k4];
        const float* wp = W + k4 * 4 * 64;
        #pragma unroll
        for (int j = 0; j < 64; j++) acc[j] += a.x * wp[j];
        #pragma unroll
        for (int j = 0; j < 64; j++) acc[j] += a.y * wp[64 + j];
        #pragma unroll
        for (int j = 0; j < 64; j++) acc[j] += a.z * wp[128 + j];
        #pragma unroll
        for (int j = 0; j < 64; j++) acc[j] += a.w * wp[192 + j];
    }
    float* orow = out + (size_t)row * ldo;
    #pragma unroll
    for (int j = 0; j < 64; j++) {
        float v = acc[j];
        if (LEAKY) v = leaky_f(v);
        if (ACCUM) v += orow[j];
        orow[j] = v;
    }
}

__global__ void leaky_kernel(float* __restrict__ x, int n) {
    int i = blockIdx.x * blockDim.x + threadIdx.x;
    if (i < n) x[i] = leaky_f(x[i]);
}

// ---------------------------------------------------------------------------
extern "C" void kernel_launch(void* const* d_in, const int* in_sizes, int n_in,
                              void* d_out, int out_size, void* d_ws, size_t ws_size,
                              hipStream_t stream) {
    const int N = in_sizes[0] / 128;
    const int E = in_sizes[2];

    const float* feat[2] = {(const float*)d_in[0], (const float*)d_in[1]};
    const int*   src[2]  = {(const int*)d_in[2], (const int*)d_in[4]};
    const int*   dstp[2] = {(const int*)d_in[3], (const int*)d_in[5]};
    const float* W1[2]   = {(const float*)d_in[6], (const float*)d_in[10]};
    const float* b1[2]   = {(const float*)d_in[7], (const float*)d_in[11]};
    const float* W2[2]   = {(const float*)d_in[8], (const float*)d_in[12]};
    const float* b2[2]   = {(const float*)d_in[9], (const float*)d_in[13]};
    const float* W3      = (const float*)d_in[14];
    const float* b3      = (const float*)d_in[15];
    float* out = (float*)d_out;

    // workspace layout (all 256B-aligned)
    char* p = (char*)d_ws;
    auto alloc = [&](size_t bytes) -> char* {
        char* r = p;
        p += (bytes + 255) & ~(size_t)255;
        return r;
    };
    float* Mcat   = (float*)alloc((size_t)192 * 64 * 4);
    float* F      = (float*)alloc((size_t)N * 192 * 4);
    float* tmp    = (float*)alloc((size_t)N * 64 * 4);
    float* dinv   = (float*)alloc((size_t)N * 4);
    int*   deg    = (int*)alloc((size_t)N * 4);
    int*   rowptr = (int*)alloc((size_t)(N + 1) * 4);
    int*   cursor = (int*)alloc((size_t)N * 4);
    int*   esrc   = (int*)alloc((size_t)E * 4);
    int*   incl   = (int*)alloc((size_t)N * 4);
    int*   bsum   = (int*)alloc((size_t)256 * 4);
    (void)ws_size; (void)n_in; (void)out_size;

    hipMemsetAsync(d_out, 0, (size_t)N * 64 * 4, stream);
    compute_M<<<(192 * 64 + 255) / 256, 256, 0, stream>>>(W3, Mcat);

    const int NB = (N + 1023) / 1024;
    for (int b = 0; b < 2; b++) {
        // --- graph build (CSR by dst) ---
        hipMemsetAsync(deg, 0, (size_t)N * 4, stream);
        deg_kernel<<<(E + 255) / 256, 256, 0, stream>>>(dstp[b], deg, E);
        scan1<<<NB, 1024, 0, stream>>>(deg, incl, bsum, N);
        scan2<<<1, 64, 0, stream>>>(bsum, NB);
        scan3<<<(N + 255) / 256, 256, 0, stream>>>(incl, bsum, deg, rowptr, cursor, dinv, N);
        scatter_kernel<<<(E + 255) / 256, 256, 0, stream>>>(src[b], dstp[b], cursor, esrc, E);

        // --- MLP: h = leaky(leaky(X@W1+b1)@W2+b2), h stored in F[:,0:64] ---
        gemm64<128, true, false><<<(N + 255) / 256, 256, 0, stream>>>(
            feat[b], 128, W1[b], b1[b], tmp, 64, N);
        gemm64<64, true, false><<<(N + 255) / 256, 256, 0, stream>>>(
            tmp, 64, W2[b], b2[b], F, 192, N);

        // --- polynomial propagation: f1 = L~ h, f2 = L~ f1 ---
        spmm_kernel<<<(N + 3) / 4, 256, 0, stream>>>(F, 0, 64, rowptr, esrc, dinv, N);
        spmm_kernel<<<(N + 3) / 4, 256, 0, stream>>>(F, 64, 128, rowptr, esrc, dinv, N);

        // --- out += [h|f1|f2] @ Mcat + b3 ---
        gemm64<192, false, true><<<(N + 255) / 256, 256, 0, stream>>>(
            F, 192, Mcat, b3, out, 64, N);
    }

    leaky_kernel<<<(N * 64 + 255) / 256, 256, 0, stream>>>(out, N * 64);
}

// Round 2
// 790.560 us; speedup vs baseline: 1.0112x; 1.0112x over previous
//
#include <hip/hip_runtime.h>

#define LEAKY_SLOPE 0.01f

__device__ __forceinline__ float leaky_f(float x) { return x > 0.f ? x : LEAKY_SLOPE * x; }

// ---------------------------------------------------------------------------
// Combine THETAS (compile-time, D=2) with W3 (192x64):
//   M[k*64 + r][c] = sum_t theta[t][k] * W3[t*64 + r][c],  k = 0..2
// so branch_out = h@M0 + f1@M1 + f2@M2 + b3.
// ---------------------------------------------------------------------------
__global__ void compute_M(const float* __restrict__ W3, float* __restrict__ M) {
    int idx = blockIdx.x * blockDim.x + threadIdx.x;
    if (idx >= 192 * 64) return;
    int c = idx & 63;
    int r = (idx >> 6) & 63;
    int k = idx >> 12;  // 0..2
    const float TH[3][3] = {{3.f, -3.f, 0.75f},
                            {0.f,  3.f, -1.5f},
                            {0.f,  0.f, 0.75f}};
    float v = 0.f;
    #pragma unroll
    for (int t = 0; t < 3; t++) v += TH[t][k] * W3[(t * 64 + r) * 64 + c];
    M[idx] = v;
}

// ---------------------------------------------------------------------------
// Graph build: degree count (int atomics), hierarchical exclusive scan,
// counting-sort scatter into CSR. Scatter stores pre-scaled payload:
//   eoff = src*192 (byte-row offset in F), ediv = dinv[src]
// so the SpMM inner loop has no dependent second gather.
// ---------------------------------------------------------------------------
__global__ void deg_kernel(const int* __restrict__ dst, int* __restrict__ deg, int E) {
    int e = blockIdx.x * blockDim.x + threadIdx.x;
    if (e < E) atomicAdd(&deg[dst[e]], 1);
}

__global__ void scan1(const int* __restrict__ deg, int* __restrict__ incl,
                      int* __restrict__ bsum, int n) {
    __shared__ int sm[1024];
    int i = blockIdx.x * 1024 + threadIdx.x;
    int v = (i < n) ? deg[i] : 0;
    sm[threadIdx.x] = v;
    __syncthreads();
    for (int off = 1; off < 1024; off <<= 1) {
        int a = (threadIdx.x >= (unsigned)off) ? sm[threadIdx.x - off] : 0;
        __syncthreads();
        sm[threadIdx.x] += a;
        __syncthreads();
    }
    if (i < n) incl[i] = sm[threadIdx.x];
    if (threadIdx.x == 1023) bsum[blockIdx.x] = sm[1023];
}

__global__ void scan2(int* __restrict__ bsum, int nb) {
    if (blockIdx.x == 0 && threadIdx.x == 0) {
        int run = 0;
        for (int b = 0; b < nb; b++) { int t = bsum[b]; bsum[b] = run; run += t; }
    }
}

__global__ void scan3(const int* __restrict__ incl, const int* __restrict__ bsum,
                      const int* __restrict__ deg, int* __restrict__ rowptr,
                      int* __restrict__ cursor, float* __restrict__ dinv, int n) {
    int i = blockIdx.x * blockDim.x + threadIdx.x;
    if (i >= n) return;
    int inc = incl[i] + bsum[i >> 10];
    int d = deg[i];
    rowptr[i + 1] = inc;
    cursor[i] = inc - d;  // exclusive scan = scatter base
    if (i == 0) rowptr[0] = 0;
    float df = (float)(d < 1 ? 1 : d);
    dinv[i] = 1.0f / sqrtf(df);
}

__global__ void scatter_kernel(const int* __restrict__ src, const int* __restrict__ dst,
                               int* __restrict__ cursor, const float* __restrict__ dinv,
                               int* __restrict__ eoff, float* __restrict__ ediv, int E) {
    int e = blockIdx.x * blockDim.x + threadIdx.x;
    if (e >= E) return;
    int s = src[e];
    int pos = atomicAdd(&cursor[dst[e]], 1);
    eoff[pos] = s * 192;
    ediv[pos] = dinv[s];
}

// ---------------------------------------------------------------------------
// SpMM: one wave per dst node, lane = feature (64 = H exactly).
// 4-wide manual unroll (+unroll 2 => 8 gathers in flight) for MLP.
// ---------------------------------------------------------------------------
__global__ void spmm_kernel(float* __restrict__ F, int in_off, int out_off,
                            const int* __restrict__ rowptr, const int* __restrict__ eoff,
                            const float* __restrict__ ediv, const float* __restrict__ dinv,
                            int n) {
    int w = (blockIdx.x * blockDim.x + threadIdx.x) >> 6;
    int j = threadIdx.x & 63;
    if (w >= n) return;
    int beg = rowptr[w];
    int end = rowptr[w + 1];
    const float* Fin = F + in_off + j;
    float a0 = 0.f, a1 = 0.f, a2 = 0.f, a3 = 0.f;
    int e = beg;
    #pragma unroll 2
    for (; e + 4 <= end; e += 4) {
        int o0 = eoff[e + 0], o1 = eoff[e + 1], o2 = eoff[e + 2], o3 = eoff[e + 3];
        float d0 = ediv[e + 0], d1 = ediv[e + 1], d2 = ediv[e + 2], d3 = ediv[e + 3];
        float v0 = Fin[o0], v1 = Fin[o1], v2 = Fin[o2], v3 = Fin[o3];
        a0 += v0 * d0;
        a1 += v1 * d1;
        a2 += v2 * d2;
        a3 += v3 * d3;
    }
    for (; e < end; e++) a0 += Fin[eoff[e]] * ediv[e];
    float acc = (a0 + a1) + (a2 + a3);
    int wo = w * 192;
    F[wo + out_off + j] = F[wo + in_off + j] - acc * dinv[w];
}

// ---------------------------------------------------------------------------
// Dense GEMM, 4x wave parallelism vs round-0: thread = (row, col-quarter).
// Lanes within a wave = 64 consecutive rows -> W/bias loads are wave-uniform.
// acc[16] per thread. Optional fused accumulate-with-out + leaky epilogue.
// ---------------------------------------------------------------------------
template <int K, bool LEAKY, bool ACCUM>
__global__ void gemm64c(const float* __restrict__ A, int lda,
                        const float* __restrict__ W, const float* __restrict__ bias,
                        float* __restrict__ out, int ldo, int n) {
    int lane = threadIdx.x & 63;
    int cg = threadIdx.x >> 6;  // 0..3
    int row = blockIdx.x * 64 + lane;
    int c0 = cg * 16;
    if (row >= n) return;
    float acc[16];
    #pragma unroll
    for (int j = 0; j < 16; j++) acc[j] = bias[c0 + j];
    const float4* arow = reinterpret_cast<const float4*>(A + (size_t)row * lda);
    #pragma unroll 1
    for (int k4 = 0; k4 < K / 4; k4++) {
        float4 a = arow[k4];
        const float* wp = W + k4 * 256 + c0;
        #pragma unroll
        for (int j = 0; j < 16; j++) acc[j] += a.x * wp[j];
        #pragma unroll
        for (int j = 0; j < 16; j++) acc[j] += a.y * wp[64 + j];
        #pragma unroll
        for (int j = 0; j < 16; j++) acc[j] += a.z * wp[128 + j];
        #pragma unroll
        for (int j = 0; j < 16; j++) acc[j] += a.w * wp[192 + j];
    }
    float* orow = out + (size_t)row * ldo + c0;
    #pragma unroll
    for (int j = 0; j < 16; j++) {
        float v = acc[j];
        if (ACCUM) v += orow[j];
        if (LEAKY) v = leaky_f(v);
        orow[j] = v;
    }
}

// ---------------------------------------------------------------------------
extern "C" void kernel_launch(void* const* d_in, const int* in_sizes, int n_in,
                              void* d_out, int out_size, void* d_ws, size_t ws_size,
                              hipStream_t stream) {
    const int N = in_sizes[0] / 128;
    const int E = in_sizes[2];

    const float* feat[2] = {(const float*)d_in[0], (const float*)d_in[1]};
    const int*   src[2]  = {(const int*)d_in[2], (const int*)d_in[4]};
    const int*   dstp[2] = {(const int*)d_in[3], (const int*)d_in[5]};
    const float* W1[2]   = {(const float*)d_in[6], (const float*)d_in[10]};
    const float* b1[2]   = {(const float*)d_in[7], (const float*)d_in[11]};
    const float* W2[2]   = {(const float*)d_in[8], (const float*)d_in[12]};
    const float* b2[2]   = {(const float*)d_in[9], (const float*)d_in[13]};
    const float* W3      = (const float*)d_in[14];
    const float* b3      = (const float*)d_in[15];
    float* out = (float*)d_out;

    // workspace layout (all 256B-aligned)
    char* p = (char*)d_ws;
    auto alloc = [&](size_t bytes) -> char* {
        char* r = p;
        p += (bytes + 255) & ~(size_t)255;
        return r;
    };
    float* Mcat   = (float*)alloc((size_t)192 * 64 * 4);
    float* F      = (float*)alloc((size_t)N * 192 * 4);
    float* dinv   = (float*)alloc((size_t)N * 4);
    int*   deg    = (int*)alloc((size_t)N * 4);
    int*   rowptr = (int*)alloc((size_t)(N + 1) * 4);
    int*   cursor = (int*)alloc((size_t)N * 4);
    int*   eoff   = (int*)alloc((size_t)E * 4);
    float* ediv   = (float*)alloc((size_t)E * 4);
    int*   incl   = (int*)alloc((size_t)N * 4);
    int*   bsum   = (int*)alloc((size_t)256 * 4);
    (void)ws_size; (void)n_in; (void)out_size;

    compute_M<<<(192 * 64 + 255) / 256, 256, 0, stream>>>(W3, Mcat);

    const int NB = (N + 1023) / 1024;
    const int GEMM_GRID = (N + 63) / 64;
    for (int b = 0; b < 2; b++) {
        // --- graph build (CSR by dst, payload pre-scaled) ---
        hipMemsetAsync(deg, 0, (size_t)N * 4, stream);
        deg_kernel<<<(E + 255) / 256, 256, 0, stream>>>(dstp[b], deg, E);
        scan1<<<NB, 1024, 0, stream>>>(deg, incl, bsum, N);
        scan2<<<1, 64, 0, stream>>>(bsum, NB);
        scan3<<<(N + 255) / 256, 256, 0, stream>>>(incl, bsum, deg, rowptr, cursor, dinv, N);
        scatter_kernel<<<(E + 255) / 256, 256, 0, stream>>>(src[b], dstp[b], cursor, dinv,
                                                            eoff, ediv, E);

        // --- MLP: tmp = leaky(X@W1+b1) stored in F[:,64:128]; h -> F[:,0:64] ---
        gemm64c<128, true, false><<<GEMM_GRID, 256, 0, stream>>>(
            feat[b], 128, W1[b], b1[b], F + 64, 192, N);
        gemm64c<64, true, false><<<GEMM_GRID, 256, 0, stream>>>(
            F + 64, 192, W2[b], b2[b], F, 192, N);

        // --- polynomial propagation: f1 = L~ h (cols 64:128), f2 = L~ f1 (128:192) ---
        spmm_kernel<<<(N * 64 + 255) / 256, 256, 0, stream>>>(F, 0, 64, rowptr, eoff, ediv, dinv, N);
        spmm_kernel<<<(N * 64 + 255) / 256, 256, 0, stream>>>(F, 64, 128, rowptr, eoff, ediv, dinv, N);

        // --- out (+)= [h|f1|f2] @ Mcat + b3 ; final leaky fused into branch 1 ---
        if (b == 0)
            gemm64c<192, false, false><<<GEMM_GRID, 256, 0, stream>>>(
                F, 192, Mcat, b3, out, 64, N);
        else
            gemm64c<192, true, true><<<GEMM_GRID, 256, 0, stream>>>(
                F, 192, Mcat, b3, out, 64, N);
    }
}

// Round 3
// 502.407 us; speedup vs baseline: 1.5911x; 1.5735x over previous
//
#include <hip/hip_runtime.h>

#define LEAKY_SLOPE 0.01f

__device__ __forceinline__ float leaky_f(float x) { return x > 0.f ? x : LEAKY_SLOPE * x; }

// ---------------------------------------------------------------------------
// Combine THETAS (compile-time, D=2) with W3 (192x64):
//   M[k*64 + r][c] = sum_t theta[t][k] * W3[t*64 + r][c],  k = 0..2
// ---------------------------------------------------------------------------
__global__ void compute_M(const float* __restrict__ W3, float* __restrict__ M) {
    int idx = blockIdx.x * blockDim.x + threadIdx.x;
    if (idx >= 192 * 64) return;
    int c = idx & 63;
    int r = (idx >> 6) & 63;
    int k = idx >> 12;  // 0..2
    const float TH[3][3] = {{3.f, -3.f, 0.75f},
                            {0.f,  3.f, -1.5f},
                            {0.f,  0.f, 0.75f}};
    float v = 0.f;
    #pragma unroll
    for (int t = 0; t < 3; t++) v += TH[t][k] * W3[(t * 64 + r) * 64 + c];
    M[idx] = v;
}

// ---------------------------------------------------------------------------
// Graph build: degree count, hierarchical scan, counting-sort scatter with
// pre-scaled payload (eoff = src*192, ediv = dinv[src]).
// ---------------------------------------------------------------------------
__global__ void deg_kernel(const int* __restrict__ dst, int* __restrict__ deg, int E) {
    int e = blockIdx.x * blockDim.x + threadIdx.x;
    if (e < E) atomicAdd(&deg[dst[e]], 1);
}

__global__ void scan1(const int* __restrict__ deg, int* __restrict__ incl,
                      int* __restrict__ bsum, int n) {
    __shared__ int sm[1024];
    int i = blockIdx.x * 1024 + threadIdx.x;
    int v = (i < n) ? deg[i] : 0;
    sm[threadIdx.x] = v;
    __syncthreads();
    for (int off = 1; off < 1024; off <<= 1) {
        int a = (threadIdx.x >= (unsigned)off) ? sm[threadIdx.x - off] : 0;
        __syncthreads();
        sm[threadIdx.x] += a;
        __syncthreads();
    }
    if (i < n) incl[i] = sm[threadIdx.x];
    if (threadIdx.x == 1023) bsum[blockIdx.x] = sm[1023];
}

__global__ void scan2(int* __restrict__ bsum, int nb) {
    if (blockIdx.x == 0 && threadIdx.x == 0) {
        int run = 0;
        for (int b = 0; b < nb; b++) { int t = bsum[b]; bsum[b] = run; run += t; }
    }
}

__global__ void scan3(const int* __restrict__ incl, const int* __restrict__ bsum,
                      const int* __restrict__ deg, int* __restrict__ rowptr,
                      int* __restrict__ cursor, float* __restrict__ dinv, int n) {
    int i = blockIdx.x * blockDim.x + threadIdx.x;
    if (i >= n) return;
    int inc = incl[i] + bsum[i >> 10];
    int d = deg[i];
    rowptr[i + 1] = inc;
    cursor[i] = inc - d;
    if (i == 0) rowptr[0] = 0;
    float df = (float)(d < 1 ? 1 : d);
    dinv[i] = 1.0f / sqrtf(df);
}

__global__ void scatter_kernel(const int* __restrict__ src, const int* __restrict__ dst,
                               int* __restrict__ cursor, const float* __restrict__ dinv,
                               int* __restrict__ eoff, float* __restrict__ ediv, int E) {
    int e = blockIdx.x * blockDim.x + threadIdx.x;
    if (e >= E) return;
    int s = src[e];
    int pos = atomicAdd(&cursor[dst[e]], 1);
    eoff[pos] = s * 192;
    ediv[pos] = dinv[s];
}

// ---------------------------------------------------------------------------
// SpMM: one wave per dst node, lane = feature. 4-wide unrolled gathers.
// ---------------------------------------------------------------------------
__global__ void spmm_kernel(float* __restrict__ F, int in_off, int out_off,
                            const int* __restrict__ rowptr, const int* __restrict__ eoff,
                            const float* __restrict__ ediv, const float* __restrict__ dinv,
                            int n) {
    int w = (blockIdx.x * blockDim.x + threadIdx.x) >> 6;
    int j = threadIdx.x & 63;
    if (w >= n) return;
    int beg = rowptr[w];
    int end = rowptr[w + 1];
    const float* Fin = F + in_off + j;
    float a0 = 0.f, a1 = 0.f, a2 = 0.f, a3 = 0.f;
    int e = beg;
    #pragma unroll 2
    for (; e + 4 <= end; e += 4) {
        int o0 = eoff[e + 0], o1 = eoff[e + 1], o2 = eoff[e + 2], o3 = eoff[e + 3];
        float d0 = ediv[e + 0], d1 = ediv[e + 1], d2 = ediv[e + 2], d3 = ediv[e + 3];
        float v0 = Fin[o0], v1 = Fin[o1], v2 = Fin[o2], v3 = Fin[o3];
        a0 += v0 * d0;
        a1 += v1 * d1;
        a2 += v2 * d2;
        a3 += v3 * d3;
    }
    for (; e < end; e++) a0 += Fin[eoff[e]] * ediv[e];
    float acc = (a0 + a1) + (a2 + a3);
    int wo = w * 192;
    F[wo + out_off + j] = F[wo + in_off + j] - acc * dinv[w];
}

// ---------------------------------------------------------------------------
// Dense GEMM v3: W + bias staged in LDS, read via ds_read_b128 broadcast
// (all lanes same address -> conflict-free, no per-lane vmem for W).
// Thread = (row = blk*64 + lane, col-quarter = tid>>6), acc[16].
// Explicit A prefetch so the one global load per k4 overlaps the 64 FMAs.
// ---------------------------------------------------------------------------
template <int K, bool LEAKY, bool ACCUM>
__global__ void gemm64w(const float* __restrict__ A, int lda,
                        const float* __restrict__ Wg, const float* __restrict__ bias,
                        float* __restrict__ out, int ldo, int n) {
    __shared__ float Ws[K * 64];
    __shared__ float bs[64];
    for (int i = threadIdx.x; i < K * 16; i += 256)
        reinterpret_cast<float4*>(Ws)[i] = reinterpret_cast<const float4*>(Wg)[i];
    if (threadIdx.x < 64) bs[threadIdx.x] = bias[threadIdx.x];
    __syncthreads();

    int lane = threadIdx.x & 63;
    int cg = threadIdx.x >> 6;  // 0..3
    int row = blockIdx.x * 64 + lane;
    int c0 = cg * 16;
    if (row >= n) return;

    float acc[16];
    #pragma unroll
    for (int j = 0; j < 16; j++) acc[j] = bs[c0 + j];

    const float4* arow = reinterpret_cast<const float4*>(A + (size_t)row * lda);
    const float4* wsv = reinterpret_cast<const float4*>(Ws) + (c0 >> 2);
    float4 a_next = arow[0];
    #pragma unroll 1
    for (int k4 = 0; k4 < K / 4; k4++) {
        float4 a = a_next;
        int nxt = (k4 + 1 < K / 4) ? (k4 + 1) : k4;
        a_next = arow[nxt];
        #pragma unroll
        for (int kk = 0; kk < 4; kk++) {
            float ak = (kk == 0) ? a.x : (kk == 1) ? a.y : (kk == 2) ? a.z : a.w;
            const float4* wrow = wsv + (k4 * 4 + kk) * 16;
            #pragma unroll
            for (int j4 = 0; j4 < 4; j4++) {
                float4 w = wrow[j4];
                acc[j4 * 4 + 0] += ak * w.x;
                acc[j4 * 4 + 1] += ak * w.y;
                acc[j4 * 4 + 2] += ak * w.z;
                acc[j4 * 4 + 3] += ak * w.w;
            }
        }
    }

    float* orow = out + (size_t)row * ldo + c0;
    #pragma unroll
    for (int j = 0; j < 16; j++) {
        float v = acc[j];
        if (ACCUM) v += orow[j];
        if (LEAKY) v = leaky_f(v);
        orow[j] = v;
    }
}

// ---------------------------------------------------------------------------
extern "C" void kernel_launch(void* const* d_in, const int* in_sizes, int n_in,
                              void* d_out, int out_size, void* d_ws, size_t ws_size,
                              hipStream_t stream) {
    const int N = in_sizes[0] / 128;
    const int E = in_sizes[2];

    const float* feat[2] = {(const float*)d_in[0], (const float*)d_in[1]};
    const int*   src[2]  = {(const int*)d_in[2], (const int*)d_in[4]};
    const int*   dstp[2] = {(const int*)d_in[3], (const int*)d_in[5]};
    const float* W1[2]   = {(const float*)d_in[6], (const float*)d_in[10]};
    const float* b1[2]   = {(const float*)d_in[7], (const float*)d_in[11]};
    const float* W2[2]   = {(const float*)d_in[8], (const float*)d_in[12]};
    const float* b2[2]   = {(const float*)d_in[9], (const float*)d_in[13]};
    const float* W3      = (const float*)d_in[14];
    const float* b3      = (const float*)d_in[15];
    float* out = (float*)d_out;

    char* p = (char*)d_ws;
    auto alloc = [&](size_t bytes) -> char* {
        char* r = p;
        p += (bytes + 255) & ~(size_t)255;
        return r;
    };
    float* Mcat   = (float*)alloc((size_t)192 * 64 * 4);
    float* F      = (float*)alloc((size_t)N * 192 * 4);
    float* dinv   = (float*)alloc((size_t)N * 4);
    int*   deg    = (int*)alloc((size_t)N * 4);
    int*   rowptr = (int*)alloc((size_t)(N + 1) * 4);
    int*   cursor = (int*)alloc((size_t)N * 4);
    int*   eoff   = (int*)alloc((size_t)E * 4);
    float* ediv   = (float*)alloc((size_t)E * 4);
    int*   incl   = (int*)alloc((size_t)N * 4);
    int*   bsum   = (int*)alloc((size_t)256 * 4);
    (void)ws_size; (void)n_in; (void)out_size;

    compute_M<<<(192 * 64 + 255) / 256, 256, 0, stream>>>(W3, Mcat);

    const int NB = (N + 1023) / 1024;
    const int GEMM_GRID = (N + 63) / 64;
    for (int b = 0; b < 2; b++) {
        // --- graph build ---
        hipMemsetAsync(deg, 0, (size_t)N * 4, stream);
        deg_kernel<<<(E + 255) / 256, 256, 0, stream>>>(dstp[b], deg, E);
        scan1<<<NB, 1024, 0, stream>>>(deg, incl, bsum, N);
        scan2<<<1, 64, 0, stream>>>(bsum, NB);
        scan3<<<(N + 255) / 256, 256, 0, stream>>>(incl, bsum, deg, rowptr, cursor, dinv, N);
        scatter_kernel<<<(E + 255) / 256, 256, 0, stream>>>(src[b], dstp[b], cursor, dinv,
                                                            eoff, ediv, E);

        // --- MLP: tmp = leaky(X@W1+b1) -> F[:,64:128]; h = leaky(tmp@W2+b2) -> F[:,0:64] ---
        gemm64w<128, true, false><<<GEMM_GRID, 256, 0, stream>>>(
            feat[b], 128, W1[b], b1[b], F + 64, 192, N);
        gemm64w<64, true, false><<<GEMM_GRID, 256, 0, stream>>>(
            F + 64, 192, W2[b], b2[b], F, 192, N);

        // --- polynomial propagation ---
        spmm_kernel<<<(N * 64 + 255) / 256, 256, 0, stream>>>(F, 0, 64, rowptr, eoff, ediv, dinv, N);
        spmm_kernel<<<(N * 64 + 255) / 256, 256, 0, stream>>>(F, 64, 128, rowptr, eoff, ediv, dinv, N);

        // --- out (+)= [h|f1|f2] @ Mcat + b3 ; final leaky fused into branch 1 ---
        if (b == 0)
            gemm64w<192, false, false><<<GEMM_GRID, 256, 0, stream>>>(
                F, 192, Mcat, b3, out, 64, N);
        else
            gemm64w<192, true, true><<<GEMM_GRID, 256, 0, stream>>>(
                F, 192, Mcat, b3, out, 64, N);
    }
}

// Round 4
// 454.026 us; speedup vs baseline: 1.7607x; 1.1066x over previous
//
#include <hip/hip_runtime.h>

#define LEAKY_SLOPE 0.01f

__device__ __forceinline__ float leaky_f(float x) { return x > 0.f ? x : LEAKY_SLOPE * x; }

// ---------------------------------------------------------------------------
// Combine THETAS (compile-time, D=2) with W3 (192x64):
//   M[k*64 + r][c] = sum_t theta[t][k] * W3[t*64 + r][c],  k = 0..2
// ---------------------------------------------------------------------------
__global__ void compute_M(const float* __restrict__ W3, float* __restrict__ M) {
    int idx = blockIdx.x * blockDim.x + threadIdx.x;
    if (idx >= 192 * 64) return;
    int c = idx & 63;
    int r = (idx >> 6) & 63;
    int k = idx >> 12;  // 0..2
    const float TH[3][3] = {{3.f, -3.f, 0.75f},
                            {0.f,  3.f, -1.5f},
                            {0.f,  0.f, 0.75f}};
    float v = 0.f;
    #pragma unroll
    for (int t = 0; t < 3; t++) v += TH[t][k] * W3[(t * 64 + r) * 64 + c];
    M[idx] = v;
}

// ---------------------------------------------------------------------------
// Batched graph build over BOTH relations: 2N nodes, 2E edges.
// Branch 1's nodes live at indices N..2N-1.
// ---------------------------------------------------------------------------
__global__ void deg2_kernel(const int* __restrict__ dst0, const int* __restrict__ dst1,
                            int* __restrict__ deg, int N, int E) {
    int e = blockIdx.x * blockDim.x + threadIdx.x;
    if (e >= 2 * E) return;
    int idx = (e >= E) ? (N + dst1[e - E]) : dst0[e];
    atomicAdd(&deg[idx], 1);
}

__global__ void scan1(const int* __restrict__ deg, int* __restrict__ incl,
                      int* __restrict__ bsum, int n) {
    __shared__ int sm[1024];
    int i = blockIdx.x * 1024 + threadIdx.x;
    int v = (i < n) ? deg[i] : 0;
    sm[threadIdx.x] = v;
    __syncthreads();
    for (int off = 1; off < 1024; off <<= 1) {
        int a = (threadIdx.x >= (unsigned)off) ? sm[threadIdx.x - off] : 0;
        __syncthreads();
        sm[threadIdx.x] += a;
        __syncthreads();
    }
    if (i < n) incl[i] = sm[threadIdx.x];
    if (threadIdx.x == 1023) bsum[blockIdx.x] = sm[1023];
}

// exclusive scan of up to 128 block sums, single block of 128 threads
__global__ void scan2(int* __restrict__ bsum, int nb) {
    __shared__ int sm[128];
    int t = threadIdx.x;
    int v = (t < nb) ? bsum[t] : 0;
    sm[t] = v;
    __syncthreads();
    for (int off = 1; off < 128; off <<= 1) {
        int a = (t >= off) ? sm[t - off] : 0;
        __syncthreads();
        sm[t] += a;
        __syncthreads();
    }
    if (t < nb) bsum[t] = sm[t] - v;  // exclusive
}

__global__ void scan3(const int* __restrict__ incl, const int* __restrict__ bsum,
                      const int* __restrict__ deg, int* __restrict__ rowptr,
                      int* __restrict__ cursor, float* __restrict__ dinv,
                      float* __restrict__ rsb, int n) {
    int i = blockIdx.x * blockDim.x + threadIdx.x;
    if (i >= n) return;
    int inc = incl[i] + bsum[i >> 10];
    int d = deg[i];
    rowptr[i + 1] = inc;
    cursor[i] = inc - d;
    if (i == 0) rowptr[0] = 0;
    float df = (float)(d < 1 ? 1 : d);
    float sq = sqrtf(df);
    rsb[i] = sq;           // sqrt(clip(deg,1))   (unscale factor)
    dinv[i] = 1.0f / sq;   // clip(deg,1)^(-1/2)
}

// counting-sort scatter: single 4B payload = global_src*64 (element offset
// into the pre-scaled 2N x 64 feature table). No dinv payload needed.
__global__ void scatter2(const int* __restrict__ src0, const int* __restrict__ dst0,
                         const int* __restrict__ src1, const int* __restrict__ dst1,
                         int* __restrict__ cursor, int* __restrict__ epay, int N, int E) {
    int e = blockIdx.x * blockDim.x + threadIdx.x;
    if (e >= 2 * E) return;
    int s, d;
    if (e >= E) { s = N + src1[e - E]; d = N + dst1[e - E]; }
    else        { s = src0[e];         d = dst0[e]; }
    int pos = atomicAdd(&cursor[d], 1);
    epay[pos] = s * 64;
}

// ---------------------------------------------------------------------------
// SpMM on pre-scaled features: Fout[u] = Fin[u] - dinv[u]^2 * sum Fin[src].
// One wave per node (2N nodes), lane = feature. Pure gather+add inner loop.
// ---------------------------------------------------------------------------
__global__ void spmm_s(const float* __restrict__ Fin, float* __restrict__ Fout,
                       const int* __restrict__ rowptr, const int* __restrict__ epay,
                       const float* __restrict__ dinv, int n2) {
    int u = (blockIdx.x * blockDim.x + threadIdx.x) >> 6;
    int j = threadIdx.x & 63;
    if (u >= n2) return;
    int beg = rowptr[u];
    int end = rowptr[u + 1];
    const float* base = Fin + j;
    float a0 = 0.f, a1 = 0.f, a2 = 0.f, a3 = 0.f;
    int e = beg;
    #pragma unroll 2
    for (; e + 4 <= end; e += 4) {
        int o0 = epay[e + 0], o1 = epay[e + 1], o2 = epay[e + 2], o3 = epay[e + 3];
        a0 += base[o0];
        a1 += base[o1];
        a2 += base[o2];
        a3 += base[o3];
    }
    for (; e < end; e++) a0 += base[epay[e]];
    float acc = (a0 + a1) + (a2 + a3);
    float di = dinv[u];
    Fout[(size_t)u * 64 + j] = Fin[(size_t)u * 64 + j] - (di * di) * acc;
}

// ---------------------------------------------------------------------------
// MLP GEMM, both branches in one dispatch. LDS-staged W (broadcast ds reads),
// 2 rows/thread (each W read feeds 8 FMAs). Block covers 128 rows of ONE
// branch: blocks [0,GB) -> branch 0, [GB,2GB) -> branch 1.
// SCALE: epilogue writes leaky(y)*dinv[u] (pre-scaled feature table).
// ---------------------------------------------------------------------------
template <int K, bool SCALE>
__global__ void gemm_mlp(const float* __restrict__ A0, const float* __restrict__ A1, int lda,
                         const float* __restrict__ Wg0, const float* __restrict__ Wg1,
                         const float* __restrict__ bias0, const float* __restrict__ bias1,
                         const float* __restrict__ dinv, float* __restrict__ out64,
                         int N, int GB) {
    __shared__ float Ws[K * 64];
    __shared__ float bs[64];
    int br = (blockIdx.x >= GB) ? 1 : 0;
    const float* Wg = br ? Wg1 : Wg0;
    const float* bias = br ? bias1 : bias0;
    for (int i = threadIdx.x; i < K * 16; i += 256)
        reinterpret_cast<float4*>(Ws)[i] = reinterpret_cast<const float4*>(Wg)[i];
    if (threadIdx.x < 64) bs[threadIdx.x] = bias[threadIdx.x];
    __syncthreads();

    int lane = threadIdx.x & 63;
    int c0 = (threadIdx.x >> 6) * 16;
    int bb = blockIdx.x - br * GB;
    int r0 = bb * 128 + lane;
    int r1 = r0 + 64;
    bool v0 = r0 < N, v1 = r1 < N;
    int r0c = v0 ? r0 : N - 1;
    int r1c = v1 ? r1 : N - 1;
    const float* A = br ? A1 : A0;

    float acc0[16], acc1[16];
    #pragma unroll
    for (int j = 0; j < 16; j++) { acc0[j] = bs[c0 + j]; acc1[j] = bs[c0 + j]; }

    const float4* a0p = reinterpret_cast<const float4*>(A + (size_t)r0c * lda);
    const float4* a1p = reinterpret_cast<const float4*>(A + (size_t)r1c * lda);
    #pragma unroll 1
    for (int k4 = 0; k4 < K / 4; k4++) {
        float4 a0 = a0p[k4];
        float4 a1 = a1p[k4];
        #pragma unroll
        for (int kk = 0; kk < 4; kk++) {
            float a0k = (kk == 0) ? a0.x : (kk == 1) ? a0.y : (kk == 2) ? a0.z : a0.w;
            float a1k = (kk == 0) ? a1.x : (kk == 1) ? a1.y : (kk == 2) ? a1.z : a1.w;
            const float4* wrow = reinterpret_cast<const float4*>(Ws + (k4 * 4 + kk) * 64 + c0);
            #pragma unroll
            for (int j4 = 0; j4 < 4; j4++) {
                float4 w = wrow[j4];
                acc0[j4 * 4 + 0] += a0k * w.x; acc0[j4 * 4 + 1] += a0k * w.y;
                acc0[j4 * 4 + 2] += a0k * w.z; acc0[j4 * 4 + 3] += a0k * w.w;
                acc1[j4 * 4 + 0] += a1k * w.x; acc1[j4 * 4 + 1] += a1k * w.y;
                acc1[j4 * 4 + 2] += a1k * w.z; acc1[j4 * 4 + 3] += a1k * w.w;
            }
        }
    }

    float s0 = SCALE ? dinv[br * N + r0c] : 1.f;
    float s1 = SCALE ? dinv[br * N + r1c] : 1.f;
    if (v0) {
        float* o = out64 + (size_t)(br * N + r0) * 64 + c0;
        #pragma unroll
        for (int j = 0; j < 16; j++) { float v = leaky_f(acc0[j]); if (SCALE) v *= s0; o[j] = v; }
    }
    if (v1) {
        float* o = out64 + (size_t)(br * N + r1) * 64 + c0;
        #pragma unroll
        for (int j = 0; j < 16; j++) { float v = leaky_f(acc1[j]); if (SCALE) v *= s1; o[j] = v; }
    }
}

// ---------------------------------------------------------------------------
// Final fused GEMM: out = leaky( sum_{branch} [h|f1|f2]@M + 2*b3 ).
// Inputs are the SCALED tables; unscale (x rs[row]) fused into the A load.
// M (192x64, 48KB) staged in LDS. 2 rows/thread.
// ---------------------------------------------------------------------------
__global__ void gemmF(const float* __restrict__ Hs, const float* __restrict__ F1s,
                      const float* __restrict__ F2s, const float* __restrict__ rsb,
                      const float* __restrict__ Mg, const float* __restrict__ b3,
                      float* __restrict__ out, int N) {
    __shared__ float Ms[192 * 64];
    __shared__ float bs[64];
    for (int i = threadIdx.x; i < 192 * 16; i += 256)
        reinterpret_cast<float4*>(Ms)[i] = reinterpret_cast<const float4*>(Mg)[i];
    if (threadIdx.x < 64) bs[threadIdx.x] = 2.f * b3[threadIdx.x];
    __syncthreads();

    int lane = threadIdx.x & 63;
    int c0 = (threadIdx.x >> 6) * 16;
    int r0 = blockIdx.x * 128 + lane;
    int r1 = r0 + 64;
    bool v0 = r0 < N, v1 = r1 < N;
    int r0c = v0 ? r0 : N - 1;
    int r1c = v1 ? r1 : N - 1;

    float acc0[16], acc1[16];
    #pragma unroll
    for (int j = 0; j < 16; j++) { acc0[j] = bs[c0 + j]; acc1[j] = bs[c0 + j]; }

    #pragma unroll
    for (int half = 0; half < 2; half++) {
        int ub = half * N;
        float s0 = rsb[ub + r0c];
        float s1 = rsb[ub + r1c];
        #pragma unroll
        for (int pa = 0; pa < 3; pa++) {
            const float* P = (pa == 0) ? Hs : (pa == 1) ? F1s : F2s;
            const float4* a0p = reinterpret_cast<const float4*>(P + (size_t)(ub + r0c) * 64);
            const float4* a1p = reinterpret_cast<const float4*>(P + (size_t)(ub + r1c) * 64);
            #pragma unroll 1
            for (int k4 = 0; k4 < 16; k4++) {
                float4 a0 = a0p[k4];
                float4 a1 = a1p[k4];
                a0.x *= s0; a0.y *= s0; a0.z *= s0; a0.w *= s0;
                a1.x *= s1; a1.y *= s1; a1.z *= s1; a1.w *= s1;
                #pragma unroll
                for (int kk = 0; kk < 4; kk++) {
                    float a0k = (kk == 0) ? a0.x : (kk == 1) ? a0.y : (kk == 2) ? a0.z : a0.w;
                    float a1k = (kk == 0) ? a1.x : (kk == 1) ? a1.y : (kk == 2) ? a1.z : a1.w;
                    const float4* wrow =
                        reinterpret_cast<const float4*>(Ms + (pa * 64 + k4 * 4 + kk) * 64 + c0);
                    #pragma unroll
                    for (int j4 = 0; j4 < 4; j4++) {
                        float4 w = wrow[j4];
                        acc0[j4 * 4 + 0] += a0k * w.x; acc0[j4 * 4 + 1] += a0k * w.y;
                        acc0[j4 * 4 + 2] += a0k * w.z; acc0[j4 * 4 + 3] += a0k * w.w;
                        acc1[j4 * 4 + 0] += a1k * w.x; acc1[j4 * 4 + 1] += a1k * w.y;
                        acc1[j4 * 4 + 2] += a1k * w.z; acc1[j4 * 4 + 3] += a1k * w.w;
                    }
                }
            }
        }
    }

    if (v0) {
        float* o = out + (size_t)r0 * 64 + c0;
        #pragma unroll
        for (int j = 0; j < 16; j++) o[j] = leaky_f(acc0[j]);
    }
    if (v1) {
        float* o = out + (size_t)r1 * 64 + c0;
        #pragma unroll
        for (int j = 0; j < 16; j++) o[j] = leaky_f(acc1[j]);
    }
}

// ---------------------------------------------------------------------------
extern "C" void kernel_launch(void* const* d_in, const int* in_sizes, int n_in,
                              void* d_out, int out_size, void* d_ws, size_t ws_size,
                              hipStream_t stream) {
    const int N = in_sizes[0] / 128;
    const int E = in_sizes[2];
    const int N2 = 2 * N;

    const float* feat0 = (const float*)d_in[0];
    const float* feat1 = (const float*)d_in[1];
    const int*   src0  = (const int*)d_in[2];
    const int*   dst0  = (const int*)d_in[3];
    const int*   src1  = (const int*)d_in[4];
    const int*   dst1  = (const int*)d_in[5];
    const float* W1_0  = (const float*)d_in[6];
    const float* b1_0  = (const float*)d_in[7];
    const float* W2_0  = (const float*)d_in[8];
    const float* b2_0  = (const float*)d_in[9];
    const float* W1_1  = (const float*)d_in[10];
    const float* b1_1  = (const float*)d_in[11];
    const float* W2_1  = (const float*)d_in[12];
    const float* b2_1  = (const float*)d_in[13];
    const float* W3    = (const float*)d_in[14];
    const float* b3    = (const float*)d_in[15];
    float* out = (float*)d_out;

    char* p = (char*)d_ws;
    auto alloc = [&](size_t bytes) -> char* {
        char* r = p;
        p += (bytes + 255) & ~(size_t)255;
        return r;
    };
    float* Mcat   = (float*)alloc((size_t)192 * 64 * 4);
    float* Hs     = (float*)alloc((size_t)N2 * 64 * 4);   // h * dinv
    float* F1s    = (float*)alloc((size_t)N2 * 64 * 4);   // f1 * dinv
    float* F2s    = (float*)alloc((size_t)N2 * 64 * 4);   // f2 * dinv (aliases MLP tmp)
    float* dinv   = (float*)alloc((size_t)N2 * 4);
    float* rsb    = (float*)alloc((size_t)N2 * 4);
    int*   deg    = (int*)alloc((size_t)N2 * 4);
    int*   rowptr = (int*)alloc((size_t)(N2 + 1) * 4);
    int*   cursor = (int*)alloc((size_t)N2 * 4);
    int*   epay   = (int*)alloc((size_t)2 * E * 4);
    int*   incl   = (int*)alloc((size_t)N2 * 4);
    int*   bsum   = (int*)alloc((size_t)128 * 4);
    float* tmp    = F2s;  // MLP hidden; dead before spmm2 writes F2s
    (void)ws_size; (void)n_in; (void)out_size;

    const int NB = (N2 + 1023) / 1024;       // 98 blocks (<128, fits scan2)
    const int GB = (N + 127) / 128;          // blocks per branch for MLP gemms

    compute_M<<<(192 * 64 + 255) / 256, 256, 0, stream>>>(W3, Mcat);

    // --- batched graph build ---
    hipMemsetAsync(deg, 0, (size_t)N2 * 4, stream);
    deg2_kernel<<<(2 * E + 255) / 256, 256, 0, stream>>>(dst0, dst1, deg, N, E);
    scan1<<<NB, 1024, 0, stream>>>(deg, incl, bsum, N2);
    scan2<<<1, 128, 0, stream>>>(bsum, NB);
    scan3<<<(N2 + 255) / 256, 256, 0, stream>>>(incl, bsum, deg, rowptr, cursor, dinv, rsb, N2);
    scatter2<<<(2 * E + 255) / 256, 256, 0, stream>>>(src0, dst0, src1, dst1, cursor, epay, N, E);

    // --- MLP (both branches): tmp = leaky(X@W1+b1); Hs = leaky(tmp@W2+b2)*dinv ---
    gemm_mlp<128, false><<<2 * GB, 256, 0, stream>>>(
        feat0, feat1, 128, W1_0, W1_1, b1_0, b1_1, dinv, tmp, N, GB);
    gemm_mlp<64, true><<<2 * GB, 256, 0, stream>>>(
        tmp, tmp + (size_t)N * 64, 64, W2_0, W2_1, b2_0, b2_1, dinv, Hs, N, GB);

    // --- polynomial propagation on scaled features ---
    spmm_s<<<(N2 * 64 + 255) / 256, 256, 0, stream>>>(Hs, F1s, rowptr, epay, dinv, N2);
    spmm_s<<<(N2 * 64 + 255) / 256, 256, 0, stream>>>(F1s, F2s, rowptr, epay, dinv, N2);

    // --- out = leaky( sum_b [h|f1|f2]@M + 2*b3 ), unscale fused ---
    gemmF<<<(N + 127) / 128, 256, 0, stream>>>(Hs, F1s, F2s, rsb, Mcat, b3, out, N);
}